// Round 14
// baseline (592.350 us; speedup 1.0000x reference)
//
#include <hip/hip_runtime.h>
#include <math.h>

#define NN 50000
#define NE 400000

typedef _Float16 f16;
typedef _Float16 f16x8 __attribute__((ext_vector_type(8)));
typedef _Float16 f16x4 __attribute__((ext_vector_type(4)));
typedef _Float16 f16x2 __attribute__((ext_vector_type(2)));
typedef float f32x4 __attribute__((ext_vector_type(4)));

static __device__ __forceinline__ float dot8(f16x8 a, f16x8 b, float acc) {
#if defined(__has_builtin) && __has_builtin(__builtin_amdgcn_fdot2)
#pragma unroll
  for (int j = 0; j < 4; ++j) {
    f16x2 x = {a[2 * j], a[2 * j + 1]};
    f16x2 y = {b[2 * j], b[2 * j + 1]};
    acc = __builtin_amdgcn_fdot2(x, y, acc, false);
  }
#else
#pragma unroll
  for (int j = 0; j < 8; ++j) acc += (float)a[j] * (float)b[j];
#endif
  return acc;
}

// 16B async global->LDS (wave-uniform LDS base + lane*16; per-lane global src)
#if defined(__has_builtin) && __has_builtin(__builtin_amdgcn_global_load_lds)
#define HAVE_GLL 1
static __device__ __forceinline__ void gload_lds16(const f16* gp, f16* lp) {
  __builtin_amdgcn_global_load_lds((const __attribute__((address_space(1))) void*)gp,
                                   (__attribute__((address_space(3))) void*)lp, 16, 0, 0);
}
#else
#define HAVE_GLL 0
#endif

// ========== hgemm_k128: K=128, A staged ONCE via global_load_lds, col-tile loop ==========
__global__ __launch_bounds__(256) void hgemm_k128_kernel(
    const f16* __restrict__ A, int lda,
    const f16* __restrict__ WT,
    const float* __restrict__ bias,
    f16* __restrict__ outb, int ldb,
    int M, int ntiles)
{
  __shared__ f16 As[128 * 128];
  __shared__ f16 Bs[64 * 128];
  const int t = threadIdx.x;
  const int wv = t >> 6, lane = t & 63;
  const int l15 = lane & 15, l4 = lane >> 4;
  const int c8 = lane & 15, rsub = lane >> 4;
  const int row0 = blockIdx.x * 128;

#if HAVE_GLL
#pragma unroll
  for (int k = 0; k < 8; ++k) {            // stage A once (swizzled source, linear dest)
    int r = wv * 4 + k * 16 + rsub;
    int rc = row0 + r; if (rc >= M) rc = M - 1;
    const f16* gp = A + (size_t)rc * lda + ((c8 ^ (r & 15)) << 3);
    gload_lds16(gp, As + (wv * 4 + k * 16) * 128);
  }
#else
  for (int i = t; i < 2048; i += 256) {
    int r = i >> 4, cc = i & 15;
    int gr = row0 + r; if (gr >= M) gr = M - 1;
    float4 v = *(const float4*)(A + (size_t)gr * lda + cc * 8);
    *(float4*)(As + r * 128 + ((cc ^ (r & 15)) << 3)) = v;
  }
#endif
  for (int ct = 0; ct < ntiles; ++ct) {
    const int col0 = (blockIdx.y * ntiles + ct) * 64;
#if HAVE_GLL
#pragma unroll
    for (int k = 0; k < 4; ++k) {
      int c = wv * 4 + k * 16 + rsub;
      const f16* gp = WT + (size_t)(col0 + c) * 128 + ((c8 ^ (c & 15)) << 3);
      gload_lds16(gp, Bs + (wv * 4 + k * 16) * 128);
    }
#else
    for (int i = t; i < 1024; i += 256) {
      int c = i >> 4, cc = i & 15;
      float4 v = *(const float4*)(WT + (size_t)(col0 + c) * 128 + cc * 8);
      *(float4*)(Bs + c * 128 + ((cc ^ (c & 15)) << 3)) = v;
    }
#endif
    __syncthreads();
    f32x4 acc[2][4];
#pragma unroll
    for (int m = 0; m < 2; ++m)
#pragma unroll
      for (int n = 0; n < 4; ++n) acc[m][n] = (f32x4){0.f, 0.f, 0.f, 0.f};
#pragma unroll
    for (int ks = 0; ks < 4; ++ks) {
      const int co = (((ks * 4 + l4) ^ l15) << 3);
      f16x8 a0 = *(const f16x8*)(As + (wv * 32 +      l15) * 128 + co);
      f16x8 a1 = *(const f16x8*)(As + (wv * 32 + 16 + l15) * 128 + co);
      f16x8 b0 = *(const f16x8*)(Bs + (     l15) * 128 + co);
      f16x8 b1 = *(const f16x8*)(Bs + (16 + l15) * 128 + co);
      f16x8 b2 = *(const f16x8*)(Bs + (32 + l15) * 128 + co);
      f16x8 b3 = *(const f16x8*)(Bs + (48 + l15) * 128 + co);
      acc[0][0] = __builtin_amdgcn_mfma_f32_16x16x32_f16(a0, b0, acc[0][0], 0, 0, 0);
      acc[0][1] = __builtin_amdgcn_mfma_f32_16x16x32_f16(a0, b1, acc[0][1], 0, 0, 0);
      acc[0][2] = __builtin_amdgcn_mfma_f32_16x16x32_f16(a0, b2, acc[0][2], 0, 0, 0);
      acc[0][3] = __builtin_amdgcn_mfma_f32_16x16x32_f16(a0, b3, acc[0][3], 0, 0, 0);
      acc[1][0] = __builtin_amdgcn_mfma_f32_16x16x32_f16(a1, b0, acc[1][0], 0, 0, 0);
      acc[1][1] = __builtin_amdgcn_mfma_f32_16x16x32_f16(a1, b1, acc[1][1], 0, 0, 0);
      acc[1][2] = __builtin_amdgcn_mfma_f32_16x16x32_f16(a1, b2, acc[1][2], 0, 0, 0);
      acc[1][3] = __builtin_amdgcn_mfma_f32_16x16x32_f16(a1, b3, acc[1][3], 0, 0, 0);
    }
    __syncthreads();
    float bv4[4];
#pragma unroll
    for (int n = 0; n < 4; ++n) bv4[n] = bias ? bias[col0 + n * 16 + l15] : 0.f;
#pragma unroll
    for (int m = 0; m < 2; ++m) {
#pragma unroll
      for (int j = 0; j < 4; ++j) {
        int r = row0 + wv * 32 + m * 16 + l4 * 4 + j;
        if (r >= M) continue;
#pragma unroll
        for (int n = 0; n < 4; ++n) {
          int c = col0 + n * 16 + l15;
          outb[(size_t)r * ldb + c] = (f16)(acc[m][n][j] + bv4[n]);
        }
      }
    }
  }
}

// ========== pgemm: small prep GEMMs (mode 0: S = V@WeT; mode 1: WABT rows) ==========
__global__ __launch_bounds__(256) void pgemm_kernel(
    const f16* __restrict__ Abase, const f16* __restrict__ Wbase,
    f16* __restrict__ Obase, int mode)
{
  __shared__ f16 As[128 * 128];
  __shared__ f16 Bs[64 * 128];
  const int t = threadIdx.x;
  const int wv = t >> 6, lane = t & 63;
  const int l15 = lane & 15, l4 = lane >> 4;
  const int c8 = lane & 15, rsub = lane >> 4;
  const int row0 = blockIdx.x * 128;
  const int z = blockIdx.z;
  const f16* A; const f16* WT; int ldw, ntiles, ih = 0, hh = 0;
  f16* Os;
  if (mode == 0) {
    A = Abase; WT = Wbase + (size_t)z * 49152; ldw = 128;
    Os = Obase + (size_t)z * 147456; ntiles = 3;
  } else {
    ih = z / 3; hh = z % 3;
    A = Abase + (size_t)z * 49152;
    WT = Wbase + (size_t)ih * 49152 + hh * 128; ldw = 384;
    Os = Obase + (size_t)ih * 114688; ntiles = 1;
  }
#if HAVE_GLL
#pragma unroll
  for (int k = 0; k < 8; ++k) {
    int r = wv * 4 + k * 16 + rsub;
    const f16* gp = A + (size_t)(row0 + r) * 128 + ((c8 ^ (r & 15)) << 3);
    gload_lds16(gp, As + (wv * 4 + k * 16) * 128);
  }
#else
  for (int i = t; i < 2048; i += 256) {
    int r = i >> 4, cc = i & 15;
    float4 v = *(const float4*)(A + (size_t)(row0 + r) * 128 + cc * 8);
    *(float4*)(As + r * 128 + ((cc ^ (r & 15)) << 3)) = v;
  }
#endif
  for (int ct = 0; ct < ntiles; ++ct) {
    const int col0 = (blockIdx.y * ntiles + ct) * 64;
#if HAVE_GLL
#pragma unroll
    for (int k = 0; k < 4; ++k) {
      int c = wv * 4 + k * 16 + rsub;
      const f16* gp = WT + (size_t)(col0 + c) * ldw + ((c8 ^ (c & 15)) << 3);
      gload_lds16(gp, Bs + (wv * 4 + k * 16) * 128);
    }
#else
    for (int i = t; i < 1024; i += 256) {
      int c = i >> 4, cc = i & 15;
      float4 v = *(const float4*)(WT + (size_t)(col0 + c) * ldw + cc * 8);
      *(float4*)(Bs + c * 128 + ((cc ^ (c & 15)) << 3)) = v;
    }
#endif
    __syncthreads();
    f32x4 acc[2][4];
#pragma unroll
    for (int m = 0; m < 2; ++m)
#pragma unroll
      for (int n = 0; n < 4; ++n) acc[m][n] = (f32x4){0.f, 0.f, 0.f, 0.f};
#pragma unroll
    for (int ks = 0; ks < 4; ++ks) {
      const int co = (((ks * 4 + l4) ^ l15) << 3);
      f16x8 a0 = *(const f16x8*)(As + (wv * 32 +      l15) * 128 + co);
      f16x8 a1 = *(const f16x8*)(As + (wv * 32 + 16 + l15) * 128 + co);
      f16x8 b0 = *(const f16x8*)(Bs + (     l15) * 128 + co);
      f16x8 b1 = *(const f16x8*)(Bs + (16 + l15) * 128 + co);
      f16x8 b2 = *(const f16x8*)(Bs + (32 + l15) * 128 + co);
      f16x8 b3 = *(const f16x8*)(Bs + (48 + l15) * 128 + co);
      acc[0][0] = __builtin_amdgcn_mfma_f32_16x16x32_f16(a0, b0, acc[0][0], 0, 0, 0);
      acc[0][1] = __builtin_amdgcn_mfma_f32_16x16x32_f16(a0, b1, acc[0][1], 0, 0, 0);
      acc[0][2] = __builtin_amdgcn_mfma_f32_16x16x32_f16(a0, b2, acc[0][2], 0, 0, 0);
      acc[0][3] = __builtin_amdgcn_mfma_f32_16x16x32_f16(a0, b3, acc[0][3], 0, 0, 0);
      acc[1][0] = __builtin_amdgcn_mfma_f32_16x16x32_f16(a1, b0, acc[1][0], 0, 0, 0);
      acc[1][1] = __builtin_amdgcn_mfma_f32_16x16x32_f16(a1, b1, acc[1][1], 0, 0, 0);
      acc[1][2] = __builtin_amdgcn_mfma_f32_16x16x32_f16(a1, b2, acc[1][2], 0, 0, 0);
      acc[1][3] = __builtin_amdgcn_mfma_f32_16x16x32_f16(a1, b3, acc[1][3], 0, 0, 0);
    }
    __syncthreads();
#pragma unroll
    for (int m = 0; m < 2; ++m) {
#pragma unroll
      for (int j = 0; j < 4; ++j) {
        int r = row0 + wv * 32 + m * 16 + l4 * 4 + j;
#pragma unroll
        for (int n = 0; n < 4; ++n) {
          int cc = col0 + n * 16 + l15;
          f16 v = (f16)acc[m][n][j];
          if (mode == 0) {
            Os[(size_t)r * 384 + cc] = v;
          } else if (r < 280) {
            int c;
            if (r < 128)      c = hh * 128 + r;
            else if (r < 256) c = 384 + hh * 128 + (r - 128);
            else              c = 768 + hh * 24 + (r - 256);
            Os[(size_t)c * 128 + cc] = v;
          }
        }
      }
    }
  }
}

// ========== hgemm2: 128-row tile, general-K, dual A, GLL staging, fused relu+resid ==========
// ctrOut: append ctr mini-GEMM -> d_out.  fatOut: append next layer's fat GEMM (14 tiles) -> nbuf.
__global__ __launch_bounds__(256) void hgemm2_kernel(
    const f16* __restrict__ A, int lda,
    const f16* __restrict__ A2, int lda2, int a2k,
    const f16* __restrict__ WT, int K,
    const float* __restrict__ bias,
    f16* __restrict__ outb, int ldb,
    const f16* __restrict__ fresid, int ldr,
    int dorelu, int M,
    const f16* __restrict__ ctrW, const float* __restrict__ ctrB,
    float* __restrict__ ctrOut,
    const f16* __restrict__ fatW, const float* __restrict__ fatB,
    f16* __restrict__ fatOut)
{
  __shared__ f16 As[128 * 128];
  __shared__ f16 Bs[128 * 128];
  const int t = threadIdx.x;
  const int wv = t >> 6, lane = t & 63;
  const int l15 = lane & 15, l4 = lane >> 4;
  const int c8 = lane & 15, rsub = lane >> 4;
  const int row0 = blockIdx.x * 128;
  const int col0 = blockIdx.y * 128;

  f32x4 acc[2][8];
#pragma unroll
  for (int m = 0; m < 2; ++m)
#pragma unroll
    for (int n = 0; n < 8; ++n) acc[m][n] = (f32x4){0.f, 0.f, 0.f, 0.f};

  for (int kc = 0; kc < K; kc += 128) {
    const f16* Ap; int koff, ldA;
    if (kc >= a2k) { Ap = A2; koff = kc - a2k; ldA = lda2; }
    else           { Ap = A;  koff = kc;       ldA = lda;  }
#if HAVE_GLL
#pragma unroll
    for (int k = 0; k < 8; ++k) {
      int r = wv * 4 + k * 16 + rsub;
      int rc = row0 + r; if (rc >= M) rc = M - 1;
      const f16* gp = Ap + (size_t)rc * ldA + koff + ((c8 ^ (r & 15)) << 3);
      gload_lds16(gp, As + (wv * 4 + k * 16) * 128);
    }
#pragma unroll
    for (int k = 0; k < 8; ++k) {
      int c = wv * 4 + k * 16 + rsub;
      const f16* gp = WT + (size_t)(col0 + c) * K + kc + ((c8 ^ (c & 15)) << 3);
      gload_lds16(gp, Bs + (wv * 4 + k * 16) * 128);
    }
#else
    for (int i = t; i < 2048; i += 256) {
      int r = i >> 4, cc = i & 15;
      int gr = row0 + r; if (gr >= M) gr = M - 1;
      float4 v = *(const float4*)(Ap + (size_t)gr * ldA + koff + cc * 8);
      *(float4*)(As + r * 128 + ((cc ^ (r & 15)) << 3)) = v;
    }
    for (int i = t; i < 2048; i += 256) {
      int c = i >> 4, cc = i & 15;
      float4 v = *(const float4*)(WT + (size_t)(col0 + c) * K + kc + cc * 8);
      *(float4*)(Bs + c * 128 + ((cc ^ (c & 15)) << 3)) = v;
    }
#endif
    __syncthreads();
#pragma unroll
    for (int ks = 0; ks < 4; ++ks) {
      const int co = (((ks * 4 + l4) ^ l15) << 3);
      f16x8 a0 = *(const f16x8*)(As + (wv * 32 +      l15) * 128 + co);
      f16x8 a1 = *(const f16x8*)(As + (wv * 32 + 16 + l15) * 128 + co);
#pragma unroll
      for (int n = 0; n < 8; ++n) {
        f16x8 b = *(const f16x8*)(Bs + (n * 16 + l15) * 128 + co);
        acc[0][n] = __builtin_amdgcn_mfma_f32_16x16x32_f16(a0, b, acc[0][n], 0, 0, 0);
        acc[1][n] = __builtin_amdgcn_mfma_f32_16x16x32_f16(a1, b, acc[1][n], 0, 0, 0);
      }
    }
    __syncthreads();
  }

  const bool stash = (ctrOut != nullptr) || (fatOut != nullptr);
  float bv8[8];
#pragma unroll
  for (int n = 0; n < 8; ++n) bv8[n] = bias ? bias[col0 + n * 16 + l15] : 0.f;
#pragma unroll
  for (int m = 0; m < 2; ++m) {
#pragma unroll
    for (int j = 0; j < 4; ++j) {
      int rl = wv * 32 + m * 16 + l4 * 4 + j;
      int r = row0 + rl;
#pragma unroll
      for (int n = 0; n < 8; ++n) {
        int c = col0 + n * 16 + l15;
        float val = acc[m][n][j] + bv8[n];
        if (fresid) val += (float)fresid[(size_t)r * ldr + c];
        if (dorelu) val = fmaxf(val, 0.f);
        f16 hv = (f16)val;
        if (r < M) outb[(size_t)r * ldb + c] = hv;
        if (stash)   // stash x_new tile into As (swizzled [row][k])
          As[rl * 128 + (((c >> 3) ^ (rl & 15)) << 3) + (c & 7)] = hv;
      }
    }
  }

  if (ctrOut) {
    // Bs <- ctrW k<128 half (h3 part)
    for (int i = t; i < 2048; i += 256) {
      int c = i >> 4, k8 = i & 15;
      float4 v = *(const float4*)(ctrW + (size_t)c * 256 + k8 * 8);
      *(float4*)(Bs + c * 128 + ((k8 ^ (c & 15)) << 3)) = v;
    }
    __syncthreads();
    f32x4 acc2[2][8];
#pragma unroll
    for (int m = 0; m < 2; ++m)
#pragma unroll
      for (int n = 0; n < 8; ++n) acc2[m][n] = (f32x4){0.f, 0.f, 0.f, 0.f};
#pragma unroll
    for (int ks = 0; ks < 4; ++ks) {
      const int co = (((ks * 4 + l4) ^ l15) << 3);
      f16x8 a0 = *(const f16x8*)(As + (wv * 32 +      l15) * 128 + co);
      f16x8 a1 = *(const f16x8*)(As + (wv * 32 + 16 + l15) * 128 + co);
#pragma unroll
      for (int n = 0; n < 8; ++n) {
        f16x8 b = *(const f16x8*)(Bs + (n * 16 + l15) * 128 + co);
        acc2[0][n] = __builtin_amdgcn_mfma_f32_16x16x32_f16(a0, b, acc2[0][n], 0, 0, 0);
        acc2[1][n] = __builtin_amdgcn_mfma_f32_16x16x32_f16(a1, b, acc2[1][n], 0, 0, 0);
      }
    }
    __syncthreads();
    // As <- h tile (xh h-half via A2), Bs <- ctrW k>=128 half
    for (int i = t; i < 2048; i += 256) {
      int r = i >> 4, k8 = i & 15;
      int gr = row0 + r; if (gr >= M) gr = M - 1;
      float4 v = *(const float4*)(A2 + (size_t)gr * lda2 + 128 + k8 * 8);
      *(float4*)(As + r * 128 + ((k8 ^ (r & 15)) << 3)) = v;
    }
    for (int i = t; i < 2048; i += 256) {
      int c = i >> 4, k8 = i & 15;
      float4 v = *(const float4*)(ctrW + (size_t)c * 256 + 128 + k8 * 8);
      *(float4*)(Bs + c * 128 + ((k8 ^ (c & 15)) << 3)) = v;
    }
    __syncthreads();
#pragma unroll
    for (int ks = 0; ks < 4; ++ks) {
      const int co = (((ks * 4 + l4) ^ l15) << 3);
      f16x8 a0 = *(const f16x8*)(As + (wv * 32 +      l15) * 128 + co);
      f16x8 a1 = *(const f16x8*)(As + (wv * 32 + 16 + l15) * 128 + co);
#pragma unroll
      for (int n = 0; n < 8; ++n) {
        f16x8 b = *(const f16x8*)(Bs + (n * 16 + l15) * 128 + co);
        acc2[0][n] = __builtin_amdgcn_mfma_f32_16x16x32_f16(a0, b, acc2[0][n], 0, 0, 0);
        acc2[1][n] = __builtin_amdgcn_mfma_f32_16x16x32_f16(a1, b, acc2[1][n], 0, 0, 0);
      }
    }
#pragma unroll
    for (int m = 0; m < 2; ++m) {
#pragma unroll
      for (int j = 0; j < 4; ++j) {
        int r = row0 + wv * 32 + m * 16 + l4 * 4 + j;
        if (r >= M) continue;
#pragma unroll
        for (int n = 0; n < 8; ++n) {
          int c = n * 16 + l15;
          ctrOut[(size_t)r * 128 + c] = acc2[m][n][j] + ctrB[c];
        }
      }
    }
  }

  if (fatOut) {
    // next layer's fat: nbuf[r][c] = x_new[r,:] @ fatW[c,:] + fatB[c], 14 x 64-col tiles
    for (int ct = 0; ct < 14; ++ct) {
      const int cf0 = ct * 64;
      for (int i = t; i < 1024; i += 256) {
        int c = i >> 4, k8 = i & 15;
        float4 v = *(const float4*)(fatW + (size_t)(cf0 + c) * 128 + k8 * 8);
        *(float4*)(Bs + c * 128 + ((k8 ^ (c & 15)) << 3)) = v;
      }
      __syncthreads();
      f32x4 acc3[2][4];
#pragma unroll
      for (int m = 0; m < 2; ++m)
#pragma unroll
        for (int n = 0; n < 4; ++n) acc3[m][n] = (f32x4){0.f, 0.f, 0.f, 0.f};
#pragma unroll
      for (int ks = 0; ks < 4; ++ks) {
        const int co = (((ks * 4 + l4) ^ l15) << 3);
        f16x8 a0 = *(const f16x8*)(As + (wv * 32 +      l15) * 128 + co);
        f16x8 a1 = *(const f16x8*)(As + (wv * 32 + 16 + l15) * 128 + co);
        f16x8 b0 = *(const f16x8*)(Bs + (     l15) * 128 + co);
        f16x8 b1 = *(const f16x8*)(Bs + (16 + l15) * 128 + co);
        f16x8 b2 = *(const f16x8*)(Bs + (32 + l15) * 128 + co);
        f16x8 b3 = *(const f16x8*)(Bs + (48 + l15) * 128 + co);
        acc3[0][0] = __builtin_amdgcn_mfma_f32_16x16x32_f16(a0, b0, acc3[0][0], 0, 0, 0);
        acc3[0][1] = __builtin_amdgcn_mfma_f32_16x16x32_f16(a0, b1, acc3[0][1], 0, 0, 0);
        acc3[0][2] = __builtin_amdgcn_mfma_f32_16x16x32_f16(a0, b2, acc3[0][2], 0, 0, 0);
        acc3[0][3] = __builtin_amdgcn_mfma_f32_16x16x32_f16(a0, b3, acc3[0][3], 0, 0, 0);
        acc3[1][0] = __builtin_amdgcn_mfma_f32_16x16x32_f16(a1, b0, acc3[1][0], 0, 0, 0);
        acc3[1][1] = __builtin_amdgcn_mfma_f32_16x16x32_f16(a1, b1, acc3[1][1], 0, 0, 0);
        acc3[1][2] = __builtin_amdgcn_mfma_f32_16x16x32_f16(a1, b2, acc3[1][2], 0, 0, 0);
        acc3[1][3] = __builtin_amdgcn_mfma_f32_16x16x32_f16(a1, b3, acc3[1][3], 0, 0, 0);
      }
#pragma unroll
      for (int m = 0; m < 2; ++m) {
#pragma unroll
        for (int j = 0; j < 4; ++j) {
          int r = row0 + wv * 32 + m * 16 + l4 * 4 + j;
          if (r >= M) continue;
#pragma unroll
          for (int n = 0; n < 4; ++n) {
            int c = cf0 + n * 16 + l15;
            fatOut[(size_t)r * 1024 + c] = (f16)(acc3[m][n][j] + fatB[c]);
          }
        }
      }
      __syncthreads();
    }
  }
}

// ================= CSR build =================
__global__ void zero_int_kernel(int* __restrict__ p, int n) {
  int i = blockIdx.x * 256 + threadIdx.x;
  if (i < n) p[i] = 0;
}
__global__ void hist_kernel(const int* __restrict__ dst, int* __restrict__ deg) {
  int e = blockIdx.x * 256 + threadIdx.x;
  if (e < NE) atomicAdd(&deg[dst[e]], 1);
}
__global__ void scanA_kernel(const int* __restrict__ deg, int* __restrict__ rowstart,
                             int* __restrict__ part) {
  __shared__ int sd[256];
  int b = blockIdx.x, t = threadIdx.x, i = b * 256 + t;
  sd[t] = (i < NN) ? deg[i] : 0;
  __syncthreads();
  for (int o = 1; o < 256; o <<= 1) {
    int v = (t >= o) ? sd[t - o] : 0;
    __syncthreads();
    sd[t] += v;
    __syncthreads();
  }
  if (i < NN) rowstart[i + 1] = sd[t];
  if (t == 255) part[b] = sd[255];
}
__global__ void scanB_kernel(int* __restrict__ part, int nb) {
  __shared__ int sd[256];
  int t = threadIdx.x;
  sd[t] = (t < nb) ? part[t] : 0;
  __syncthreads();
  for (int o = 1; o < 256; o <<= 1) {
    int v = (t >= o) ? sd[t - o] : 0;
    __syncthreads();
    sd[t] += v;
    __syncthreads();
  }
  if (t < nb) part[t] = sd[t];
}
__global__ void scanC_kernel(const int* __restrict__ deg, int* __restrict__ rowstart,
                             const int* __restrict__ part, int* __restrict__ cursor) {
  int b = blockIdx.x, t = threadIdx.x, i = b * 256 + t;
  if (i >= NN) return;
  int off = b ? part[b - 1] : 0;
  int fin = rowstart[i + 1] + off;
  rowstart[i + 1] = fin;
  cursor[i] = fin - deg[i];
  if (i == 0) rowstart[0] = 0;
}
__global__ void scatter_kernel(const int* __restrict__ dst, const int* __restrict__ src,
                               const float* __restrict__ dirw, const float* __restrict__ geo,
                               int* __restrict__ cursor,
                               int* __restrict__ srcp, f16* __restrict__ dirpb,
                               f16* __restrict__ geop) {
  int e = blockIdx.x * 256 + threadIdx.x;
  if (e < NE) {
    int pos = atomicAdd(&cursor[dst[e]], 1);
    srcp[pos] = src[e];
    float dv = dirw[e];
    dirpb[pos] = (f16)dv;
    f16* gp = geop + (size_t)pos * 24;
#pragma unroll
    for (int j = 0; j < 20; ++j) gp[j] = (f16)geo[(size_t)e * 20 + j];
    gp[20] = (f16)dv;
    gp[21] = (f16)0.f; gp[22] = (f16)0.f; gp[23] = (f16)0.f;
  }
}

// ========== prep inputs: Vf16 (gathered Wee rows + bee), WeT16, Wq16, Wk16 ==========
__global__ void convert_kernel(const float* __restrict__ Wee, const float* __restrict__ bee,
                               const float* __restrict__ WeAll, const float* __restrict__ Wq,
                               const float* __restrict__ Wk,
                               f16* __restrict__ Vf, f16* __restrict__ WeT,
                               f16* __restrict__ Wq16, f16* __restrict__ Wk16)
{
  int idx = blockIdx.x * 256 + threadIdx.x;
  if (idx < 49152) {                       // Vf [384 rows][128]
    int r = idx >> 7, j = idx & 127;
    float v = 0.f;
    if (r < 128)       v = Wee[(size_t)(128 + r) * 128 + j];   // U rows (h[src]*dir block)
    else if (r < 256)  v = Wee[(size_t)(r - 128) * 128 + j];   // T rows (h[dst] block)
    else if (r < 276)  v = Wee[(size_t)(257 + (r - 256)) * 128 + j];  // geo rows
    else if (r == 276) v = Wee[(size_t)256 * 128 + j];         // dir row (t=20)
    else if (r == 277) v = bee[j];
    Vf[idx] = (f16)v;
  } else if (idx < 196608) {               // WeT16[i][c(384)][j(128)] = We[i][j][c]
    int rr = idx - 49152; int i = rr / 49152; int r2 = rr % 49152;
    int cc = r2 >> 7, j = r2 & 127;
    WeT[rr] = (f16)WeAll[((size_t)i * 128 + j) * 384 + cc];
  } else if (idx < 344064) {               // Wq16 straight convert
    int rr = idx - 196608;
    Wq16[rr] = (f16)Wq[rr];
  } else if (idx < 491520) {               // Wk16 straight convert
    int rr = idx - 344064;
    Wk16[rr] = (f16)Wk[rr];
  }
}

// ========== postS: Arows + W2bigT + biasAB (all depend only on Sall/Wk16/raw weights) ==========
__global__ void postS_kernel(const f16* __restrict__ Wk16, const f16* __restrict__ Sall,
                             const float* __restrict__ beAll, const float* __restrict__ Wv,
                             const float* __restrict__ bv, const float* __restrict__ Ws,
                             const float* __restrict__ Wres, const float* __restrict__ bq,
                             f16* __restrict__ Arows, f16* __restrict__ W2bigT,
                             float* __restrict__ biasAB)
{
  int idx = blockIdx.x * 256 + threadIdx.x;
  if (idx < 442368) {                      // Arows[z=(i,h)][384 rows][128]
    int z = idx / 49152; int rr = idx % 49152; int r = rr >> 7; int k2 = rr & 127;
    int i = z / 3, h = z % 3;
    f16 v = (f16)0.f;
    if (r < 128)       v = Wk16[(size_t)i * 49152 + (size_t)r * 384 + h * 128 + k2];
    else if (r < 256)  v = Sall[(size_t)i * 147456 + (size_t)(r - 128) * 384 + h * 128 + k2];
    else if (r < 277)  v = Sall[(size_t)i * 147456 + (size_t)r * 384 + h * 128 + k2];
    Arows[idx] = v;
  } else if (idx < 884736) {               // W2bigT[3l][128c][1152k]
    int r0 = idx - 442368;
    int i = r0 / 147456; int r = r0 % 147456; int c = r / 1152; int k = r % 1152;
    const f16* S = Sall + (size_t)i * 147456;
    float v = 0.f;
    if (k < 384) {
      int h = k >> 7, tt = k & 127;
      v = (float)S[(size_t)tt * 384 + h * 128 + c];
    } else if (k < 768) {
      int h = (k - 384) >> 7, u = (k - 384) & 127;
      v = Wv[((size_t)i * 128 + u) * 384 + h * 128 + c];
    } else if (k < 840) {
      int h = (k - 768) / 24, tt = (k - 768) % 24;
      if (tt < 21)       v = (float)S[(size_t)(256 + tt) * 384 + h * 128 + c];
      else if (tt == 21) v = (float)S[(size_t)277 * 384 + h * 128 + c]
                           + beAll[i * 384 + h * 128 + c] + bv[i * 384 + h * 128 + c];
    } else if (k < 896) {
      v = 0.f;
    } else if (k < 1024) {
      int tt = k - 896;
      v = ((float)S[(size_t)(128 + tt) * 384 + c]
         + (float)S[(size_t)(128 + tt) * 384 + 128 + c]
         + (float)S[(size_t)(128 + tt) * 384 + 256 + c]) * (1.0f / 3.0f);
    } else {
      v = Ws[((size_t)i * 128 + (k - 1024)) * 128 + c];
      if (i == 0) v += Wres[(k - 1024) * 128 + c];
    }
    W2bigT[(size_t)i * 147456 + c * 1152 + k] = (f16)v;
  } else if (idx < 887424) {               // biasAB[3][896]
    int r = idx - 884736; int i = r / 896; int c = r % 896;
    float acc = 0.f;
    int h = 0, ro = -1;
    if (c < 384)      { h = c >> 7;         ro = c & 127; }
    else if (c < 768) { h = (c - 384) >> 7; ro = 128 + ((c - 384) & 127); }
    else if (c < 840) { h = (c - 768) / 24; ro = 256 + ((c - 768) % 24); }
    if (ro >= 0) {
      const f16* ar = Arows + ((size_t)(i * 3 + h)) * 49152 + (size_t)ro * 128;
      const float* bqh = bq + i * 384 + h * 128;
      for (int k2 = 0; k2 < 128; ++k2) acc += (float)ar[k2] * bqh[k2];
    }
    biasAB[r] = acc;
  }
}

// ========== misc: hconv (h->xh both halves) + WctrT2 + bias0 ==========
__global__ void misc_kernel(const float* __restrict__ src, f16* __restrict__ xh,
                            const float* __restrict__ Wctr, const float* __restrict__ bs,
                            const float* __restrict__ bres,
                            f16* __restrict__ WctrT2, float* __restrict__ bias0)
{
  int idx = blockIdx.x * 256 + threadIdx.x;
  if (idx < NN * 32) {
    float4 a = ((const float4*)src)[idx];
    f16x4 o;
    o[0] = (f16)a.x; o[1] = (f16)a.y; o[2] = (f16)a.z; o[3] = (f16)a.w;
    int r = idx >> 5, c4 = idx & 31;
    *(f16x4*)(xh + (size_t)r * 256 + c4 * 4) = o;
    *(f16x4*)(xh + (size_t)r * 256 + 128 + c4 * 4) = o;
  } else if (idx < NN * 32 + 32768) {
    int r = idx - NN * 32;
    int c = r >> 8, k = r & 255;
    float v = (k < 128) ? Wctr[(size_t)(128 + k) * 128 + c]
                        : Wctr[(size_t)(k - 128) * 128 + c];
    WctrT2[r] = (f16)v;
  } else if (idx < NN * 32 + 32896) {
    int c = idx - NN * 32 - 32768;
    bias0[c] = bs[c] + bres[c];
  }
}

// ========== attention (proven): 16 lanes/node, 2-edge unroll, xh-interleaved gather ==========
__global__ __launch_bounds__(256) void attn_kernel(
    const f16* __restrict__ xh,     // [N][256] = [x | h]
    f16* __restrict__ nbuf,
    const int* __restrict__ rowstart,
    const int* __restrict__ srcp,
    const f16* __restrict__ dirpb,
    const f16* __restrict__ geop)
{
  const int sl = threadIdx.x & 15;
  const int n = blockIdx.x * 16 + (threadIdx.x >> 4);
  const float rsC = 0.088388347648318447f;  // 1/sqrt(128)
  f16* row = nbuf + (size_t)n * 1024;

  f16x8 qk[3], g2[3];
#pragma unroll
  for (int h = 0; h < 3; ++h) {
    qk[h] = *(const f16x8*)(row + h * 128 + sl * 8);
    g2[h] = *(const f16x8*)(row + 384 + h * 128 + sl * 8);
  }
  float g34a[3], g34c[3];
#pragma unroll
  for (int h = 0; h < 3; ++h) {
    g34a[h] = (float)row[768 + h * 24 + sl];
    g34c[h] = (sl < 8) ? (float)row[768 + h * 24 + 16 + sl] : 0.f;
  }
  float den[3] = {0.f, 0.f, 0.f};
  float F2[3][8], Fv[3][8];
#pragma unroll
  for (int h = 0; h < 3; ++h)
#pragma unroll
    for (int j = 0; j < 8; ++j) { F2[h][j] = 0.f; Fv[h][j] = 0.f; }
  float f34a[3] = {0.f, 0.f, 0.f}, f34c[3] = {0.f, 0.f, 0.f};

  const int beg = rowstart[n], end = rowstart[n + 1];
  int ii = beg;
  for (; ii + 1 < end; ii += 2) {
    const int s0 = srcp[ii], s1 = srcp[ii + 1];
    const float d0 = (float)dirpb[ii], d1 = (float)dirpb[ii + 1];
    const f16* p0 = xh + (size_t)s0 * 256 + sl * 8;
    const f16* p1 = xh + (size_t)s1 * 256 + sl * 8;
    f16x8 xv0 = *(const f16x8*)p0;
    f16x8 hv0 = *(const f16x8*)(p0 + 128);
    f16x8 xv1 = *(const f16x8*)p1;
    f16x8 hv1 = *(const f16x8*)(p1 + 128);
    const float gea0 = (float)geop[(size_t)ii * 24 + sl];
    const float geb0 = (sl < 8) ? (float)geop[(size_t)ii * 24 + 16 + sl] : 0.f;
    const float gea1 = (float)geop[(size_t)(ii + 1) * 24 + sl];
    const float geb1 = (sl < 8) ? (float)geop[(size_t)(ii + 1) * 24 + 16 + sl] : 0.f;

    float pa[6];
#pragma unroll
    for (int h = 0; h < 3; ++h) {
      pa[h]     = dot8(qk[h], xv0, 0.f) + d0 * dot8(g2[h], hv0, 0.f)
                + gea0 * g34a[h] + geb0 * g34c[h];
      pa[3 + h] = dot8(qk[h], xv1, 0.f) + d1 * dot8(g2[h], hv1, 0.f)
                + gea1 * g34a[h] + geb1 * g34c[h];
    }
#pragma unroll
    for (int off = 1; off < 16; off <<= 1) {
#pragma unroll
      for (int q = 0; q < 6; ++q) pa[q] += __shfl_xor(pa[q], off);
    }
    float w0[3], w1[3];
#pragma unroll
    for (int h = 0; h < 3; ++h) {
      w0[h] = __expf(pa[h] * rsC);
      w1[h] = __expf(pa[3 + h] * rsC);
      den[h] += w0[h] + w1[h];
    }
#pragma unroll
    for (int h = 0; h < 3; ++h) {
      const float wd0 = w0[h] * d0, wd1 = w1[h] * d1;
#pragma unroll
      for (int j = 0; j < 8; ++j) {
        F2[h][j] = fmaf(wd0, (float)hv0[j], fmaf(wd1, (float)hv1[j], F2[h][j]));
        Fv[h][j] = fmaf(w0[h], (float)xv0[j], fmaf(w1[h], (float)xv1[j], Fv[h][j]));
      }
      f34a[h] = fmaf(w0[h], gea0, fmaf(w1[h], gea1, f34a[h]));
      f34c[h] = fmaf(w0[h], geb0, fmaf(w1[h], geb1, f34c[h]));
    }
  }
  if (ii < end) {
    const int s0 = srcp[ii];
    const float d0 = (float)dirpb[ii];
    const f16* p0 = xh + (size_t)s0 * 256 + sl * 8;
    f16x8 xv0 = *(const f16x8*)p0;
    f16x8 hv0 = *(const f16x8*)(p0 + 128);
    const float gea0 = (float)geop[(size_t)ii * 24 + sl];
    const float geb0 = (sl < 8) ? (float)geop[(size_t)ii * 24 + 16 + sl] : 0.f;
    float pa[3];
#pragma unroll
    for (int h = 0; h < 3; ++h)
      pa[h] = dot8(qk[h], xv0, 0.f) + d0 * dot8(g2[h], hv0, 0.f)
            + gea0 * g34a[h] + geb0 * g34c[h];
#pragma unroll
    for (int off = 1; off < 16; off <<= 1) {
#pragma unroll
      for (int q = 0; q < 3; ++q) pa[q] += __shfl_xor(pa[q], off);
    }
#pragma unroll
    for (int h = 0; h < 3; ++h) {
      const float w = __expf(pa[h] * rsC);
      den[h] += w;
      const float wd = w * d0;
#pragma unroll
      for (int j = 0; j < 8; ++j) {
        F2[h][j] = fmaf(wd, (float)hv0[j], F2[h][j]);
        Fv[h][j] = fmaf(w, (float)xv0[j], Fv[h][j]);
      }
      f34a[h] = fmaf(w, gea0, f34a[h]);
      f34c[h] = fmaf(w, geb0, f34c[h]);
    }
  }

  float sc[3], swh[3];
#pragma unroll
  for (int h = 0; h < 3; ++h) {
    sc[h] = (1.f / 3.f) / (den[h] + 1e-16f);
    swh[h] = den[h] * sc[h];
  }
#pragma unroll
  for (int h = 0; h < 3; ++h) {
    f16x8 o1, o2;
#pragma unroll
    for (int j = 0; j < 8; ++j) {
      o1[j] = (f16)(F2[h][j] * sc[h]);
      o2[j] = (f16)(Fv[h][j] * sc[h]);
    }
    *(f16x8*)(row + h * 128 + sl * 8) = o1;
    *(f16x8*)(row + 384 + h * 128 + sl * 8) = o2;
  }
#pragma unroll
  for (int h = 0; h < 3; ++h) {
    row[768 + h * 24 + sl] = (f16)(f34a[h] * sc[h]);
    if (sl < 8) {
      float fcv = (sl == 5) ? swh[h] : f34c[h] * sc[h];
      row[768 + h * 24 + 16 + sl] = (f16)fcv;
    }
  }
  // masked h -> cols 896..1023 (feeds Wsum0 block of the output GEMM)
  f16x8 ho = *(const f16x8*)(xh + (size_t)n * 256 + 128 + sl * 8);
  if (beg >= end) {
#pragma unroll
    for (int j = 0; j < 8; ++j) ho[j] = (f16)0.f;
  }
  *(f16x8*)(row + 896 + sl * 8) = ho;
}

// ================= launch =================
extern "C" void kernel_launch(void* const* d_in, const int* in_sizes, int n_in,
                              void* d_out, int out_size, void* d_ws, size_t ws_size,
                              hipStream_t stream)
{
  (void)in_sizes; (void)n_in; (void)out_size; (void)ws_size;
  const float* h    = (const float*)d_in[0];
  const float* geo  = (const float*)d_in[1];
  const float* dirw = (const float*)d_in[2];
  const int*   src  = (const int*)d_in[3];
  const int*   dst  = (const int*)d_in[4];
  const float* Wee  = (const float*)d_in[5];
  const float* bee  = (const float*)d_in[6];
  const float* Wres = (const float*)d_in[7];
  const float* bres = (const float*)d_in[8];
  const float* Wq   = (const float*)d_in[9];
  const float* bq   = (const float*)d_in[10];
  const float* Wk   = (const float*)d_in[11];
  const float* bk   = (const float*)d_in[12];  (void)bk;   // cancels in softmax
  const float* Wv   = (const float*)d_in[13];
  const float* bv   = (const float*)d_in[14];
  const float* We   = (const float*)d_in[15];
  const float* be   = (const float*)d_in[16];
  const float* Ws   = (const float*)d_in[17];
  const float* bs   = (const float*)d_in[18];
  const float* Wctr = (const float*)d_in[19];
  const float* bctr = (const float*)d_in[20];

  char* base = (char*)d_ws;
  size_t off = 0;
  auto take = [&](size_t bytes) -> char* {
    char* p = base + off;
    off += bytes;
    off = (off + 255) & ~(size_t)255;
    return p;
  };
  f16* nbuf     = (f16*)take((size_t)NN * 1024 * 2);
  f16* xh       = (f16*)take((size_t)NN * 256 * 2);
  f16* Vf16     = (f16*)take(49152 * 2);
  f16* WeT16    = (f16*)take((size_t)3 * 49152 * 2);
  f16* Wq16     = (f16*)take((size_t)3 * 49152 * 2);
  f16* Wk16     = (f16*)take((size_t)3 * 49152 * 2);
  f16* Sall     = (f16*)take((size_t)3 * 147456 * 2);
  f16* Arows    = (f16*)take((size_t)9 * 49152 * 2);
  f16* WABT     = (f16*)take((size_t)3 * 114688 * 2);
  float* biasAB = (float*)take((size_t)3 * 896 * 4);
  f16* W2bigT   = (f16*)take((size_t)3 * 147456 * 2);
  f16* WctrT2   = (f16*)take(32768 * 2);
  float* bias0  = (float*)take(128 * 4);
  f16* dirpb    = (f16*)take((size_t)NE * 2);
  f16* geop     = (f16*)take((size_t)NE * 24 * 2);
  int* deg      = (int*)take((size_t)NN * 4);
  int* rowstart = (int*)take((size_t)(NN + 1) * 4);
  int* cursor   = (int*)take((size_t)NN * 4);
  int* srcp     = (int*)take((size_t)NE * 4);
  int* part     = (int*)take(256 * 4);

  // CSR by dst
  zero_int_kernel<<<(NN + 255) / 256, 256, 0, stream>>>(deg, NN);
  hist_kernel<<<(NE + 255) / 256, 256, 0, stream>>>(dst, deg);
  scanA_kernel<<<196, 256, 0, stream>>>(deg, rowstart, part);
  scanB_kernel<<<1, 256, 0, stream>>>(part, 196);
  scanC_kernel<<<196, 256, 0, stream>>>(deg, rowstart, part, cursor);
  scatter_kernel<<<(NE + 255) / 256, 256, 0, stream>>>(dst, src, dirw, geo, cursor,
                                                       srcp, dirpb, geop);
  misc_kernel<<<(NN * 32 + 32896 + 255) / 256, 256, 0, stream>>>(h, xh, Wctr, bs, bres,
                                                                 WctrT2, bias0);
  // ---- weight prep via MFMA GEMMs ----
  convert_kernel<<<(491520 + 255) / 256, 256, 0, stream>>>(Wee, bee, We, Wq, Wk,
                                                           Vf16, WeT16, Wq16, Wk16);
  pgemm_kernel<<<dim3(3, 2, 3), 256, 0, stream>>>(Vf16, WeT16, Sall, 0);      // S = V@We
  postS_kernel<<<(887424 + 255) / 256, 256, 0, stream>>>(Wk16, Sall, be, Wv, bv, Ws,
                                                         Wres, bq, Arows, W2bigT, biasAB);
  pgemm_kernel<<<dim3(3, 2, 9), 256, 0, stream>>>(Arows, Wq16, WABT, 1);      // WABT

  // layer-0 fat: h @ [qk|g2|g34|0] -> nbuf cols 0..895
  hgemm_k128_kernel<<<dim3(391, 2), 256, 0, stream>>>(xh, 256, WABT, biasAB, nbuf, 1024, NN, 7);

  for (int i = 0; i < 3; ++i) {
    // attention: rewrites nbuf cols 0..839, writes masked-h to 896..1023
    attn_kernel<<<3125, 256, 0, stream>>>(xh, nbuf, rowstart, srcp, dirpb, geop);
    // out: x_new = relu([F2|Fv|fg|0|mask*h| x(A2)] @ W2big + bias (+x resid for i>0)) -> xh x-half
    // i<2: fuses NEXT layer's fat GEMM -> nbuf.  i==2: fuses ctr GEMM -> d_out.
    const float* obias = (i == 0) ? bias0 : (bs + i * 128);
    const f16* resid = (i == 0) ? nullptr : xh;   // layer0 residual folded into W2bigT/bias0
    const f16* ctrW = (i == 2) ? WctrT2 : nullptr;
    const float* ctrB = (i == 2) ? bctr : nullptr;
    float* ctrOut = (i == 2) ? (float*)d_out : nullptr;
    const f16* fatW = (i < 2) ? (WABT + (size_t)(i + 1) * 114688) : nullptr;
    const float* fatB = (i < 2) ? (biasAB + (size_t)(i + 1) * 896) : nullptr;
    f16* fatOut = (i < 2) ? nbuf : nullptr;
    hgemm2_kernel<<<dim3(391, 1), 256, 0, stream>>>(nbuf, 1024, xh, 256, 1024,
        W2bigT + (size_t)i * 147456, 1152, obias, xh, 256,
        resid, 256, 1, NN, ctrW, ctrB, ctrOut, fatW, fatB, fatOut);
  }
}

// Round 15
// 568.465 us; speedup vs baseline: 1.0420x; 1.0420x over previous
//
#include <hip/hip_runtime.h>
#include <math.h>

#define NN 50000
#define NE 400000

typedef _Float16 f16;
typedef _Float16 f16x8 __attribute__((ext_vector_type(8)));
typedef _Float16 f16x4 __attribute__((ext_vector_type(4)));
typedef _Float16 f16x2 __attribute__((ext_vector_type(2)));
typedef float f32x4 __attribute__((ext_vector_type(4)));

static __device__ __forceinline__ float dot8(f16x8 a, f16x8 b, float acc) {
#if defined(__has_builtin) && __has_builtin(__builtin_amdgcn_fdot2)
#pragma unroll
  for (int j = 0; j < 4; ++j) {
    f16x2 x = {a[2 * j], a[2 * j + 1]};
    f16x2 y = {b[2 * j], b[2 * j + 1]};
    acc = __builtin_amdgcn_fdot2(x, y, acc, false);
  }
#else
#pragma unroll
  for (int j = 0; j < 8; ++j) acc += (float)a[j] * (float)b[j];
#endif
  return acc;
}

// 16B async global->LDS (wave-uniform LDS base + lane*16; per-lane global src)
#if defined(__has_builtin) && __has_builtin(__builtin_amdgcn_global_load_lds)
#define HAVE_GLL 1
static __device__ __forceinline__ void gload_lds16(const f16* gp, f16* lp) {
  __builtin_amdgcn_global_load_lds((const __attribute__((address_space(1))) void*)gp,
                                   (__attribute__((address_space(3))) void*)lp, 16, 0, 0);
}
#else
#define HAVE_GLL 0
#endif

// ========== hgemm_k128: K=128, A staged ONCE via global_load_lds, col-tile loop ==========
__global__ __launch_bounds__(256) void hgemm_k128_kernel(
    const f16* __restrict__ A, int lda,
    const f16* __restrict__ WT,
    const float* __restrict__ bias,
    f16* __restrict__ outb, int ldb,
    int M, int ntiles)
{
  __shared__ f16 As[128 * 128];
  __shared__ f16 Bs[64 * 128];
  const int t = threadIdx.x;
  const int wv = t >> 6, lane = t & 63;
  const int l15 = lane & 15, l4 = lane >> 4;
  const int c8 = lane & 15, rsub = lane >> 4;
  const int row0 = blockIdx.x * 128;

#if HAVE_GLL
#pragma unroll
  for (int k = 0; k < 8; ++k) {            // stage A once (swizzled source, linear dest)
    int r = wv * 4 + k * 16 + rsub;
    int rc = row0 + r; if (rc >= M) rc = M - 1;
    const f16* gp = A + (size_t)rc * lda + ((c8 ^ (r & 15)) << 3);
    gload_lds16(gp, As + (wv * 4 + k * 16) * 128);
  }
#else
  for (int i = t; i < 2048; i += 256) {
    int r = i >> 4, cc = i & 15;
    int gr = row0 + r; if (gr >= M) gr = M - 1;
    float4 v = *(const float4*)(A + (size_t)gr * lda + cc * 8);
    *(float4*)(As + r * 128 + ((cc ^ (r & 15)) << 3)) = v;
  }
#endif
  for (int ct = 0; ct < ntiles; ++ct) {
    const int col0 = (blockIdx.y * ntiles + ct) * 64;
#if HAVE_GLL
#pragma unroll
    for (int k = 0; k < 4; ++k) {
      int c = wv * 4 + k * 16 + rsub;
      const f16* gp = WT + (size_t)(col0 + c) * 128 + ((c8 ^ (c & 15)) << 3);
      gload_lds16(gp, Bs + (wv * 4 + k * 16) * 128);
    }
#else
    for (int i = t; i < 1024; i += 256) {
      int c = i >> 4, cc = i & 15;
      float4 v = *(const float4*)(WT + (size_t)(col0 + c) * 128 + cc * 8);
      *(float4*)(Bs + c * 128 + ((cc ^ (c & 15)) << 3)) = v;
    }
#endif
    __syncthreads();
    f32x4 acc[2][4];
#pragma unroll
    for (int m = 0; m < 2; ++m)
#pragma unroll
      for (int n = 0; n < 4; ++n) acc[m][n] = (f32x4){0.f, 0.f, 0.f, 0.f};
#pragma unroll
    for (int ks = 0; ks < 4; ++ks) {
      const int co = (((ks * 4 + l4) ^ l15) << 3);
      f16x8 a0 = *(const f16x8*)(As + (wv * 32 +      l15) * 128 + co);
      f16x8 a1 = *(const f16x8*)(As + (wv * 32 + 16 + l15) * 128 + co);
      f16x8 b0 = *(const f16x8*)(Bs + (     l15) * 128 + co);
      f16x8 b1 = *(const f16x8*)(Bs + (16 + l15) * 128 + co);
      f16x8 b2 = *(const f16x8*)(Bs + (32 + l15) * 128 + co);
      f16x8 b3 = *(const f16x8*)(Bs + (48 + l15) * 128 + co);
      acc[0][0] = __builtin_amdgcn_mfma_f32_16x16x32_f16(a0, b0, acc[0][0], 0, 0, 0);
      acc[0][1] = __builtin_amdgcn_mfma_f32_16x16x32_f16(a0, b1, acc[0][1], 0, 0, 0);
      acc[0][2] = __builtin_amdgcn_mfma_f32_16x16x32_f16(a0, b2, acc[0][2], 0, 0, 0);
      acc[0][3] = __builtin_amdgcn_mfma_f32_16x16x32_f16(a0, b3, acc[0][3], 0, 0, 0);
      acc[1][0] = __builtin_amdgcn_mfma_f32_16x16x32_f16(a1, b0, acc[1][0], 0, 0, 0);
      acc[1][1] = __builtin_amdgcn_mfma_f32_16x16x32_f16(a1, b1, acc[1][1], 0, 0, 0);
      acc[1][2] = __builtin_amdgcn_mfma_f32_16x16x32_f16(a1, b2, acc[1][2], 0, 0, 0);
      acc[1][3] = __builtin_amdgcn_mfma_f32_16x16x32_f16(a1, b3, acc[1][3], 0, 0, 0);
    }
    __syncthreads();
    float bv4[4];
#pragma unroll
    for (int n = 0; n < 4; ++n) bv4[n] = bias ? bias[col0 + n * 16 + l15] : 0.f;
#pragma unroll
    for (int m = 0; m < 2; ++m) {
#pragma unroll
      for (int j = 0; j < 4; ++j) {
        int r = row0 + wv * 32 + m * 16 + l4 * 4 + j;
        if (r >= M) continue;
#pragma unroll
        for (int n = 0; n < 4; ++n) {
          int c = col0 + n * 16 + l15;
          outb[(size_t)r * ldb + c] = (f16)(acc[m][n][j] + bv4[n]);
        }
      }
    }
  }
}

// ========== pgemm: small prep GEMMs (mode 0: S = V@WeT; mode 1: WABT rows) ==========
__global__ __launch_bounds__(256) void pgemm_kernel(
    const f16* __restrict__ Abase, const f16* __restrict__ Wbase,
    f16* __restrict__ Obase, int mode)
{
  __shared__ f16 As[128 * 128];
  __shared__ f16 Bs[64 * 128];
  const int t = threadIdx.x;
  const int wv = t >> 6, lane = t & 63;
  const int l15 = lane & 15, l4 = lane >> 4;
  const int c8 = lane & 15, rsub = lane >> 4;
  const int row0 = blockIdx.x * 128;
  const int z = blockIdx.z;
  const f16* A; const f16* WT; int ldw, ntiles, ih = 0, hh = 0;
  f16* Os;
  if (mode == 0) {
    A = Abase; WT = Wbase + (size_t)z * 49152; ldw = 128;
    Os = Obase + (size_t)z * 147456; ntiles = 3;
  } else {
    ih = z / 3; hh = z % 3;
    A = Abase + (size_t)z * 49152;
    WT = Wbase + (size_t)ih * 49152 + hh * 128; ldw = 384;
    Os = Obase + (size_t)ih * 114688; ntiles = 1;
  }
#if HAVE_GLL
#pragma unroll
  for (int k = 0; k < 8; ++k) {
    int r = wv * 4 + k * 16 + rsub;
    const f16* gp = A + (size_t)(row0 + r) * 128 + ((c8 ^ (r & 15)) << 3);
    gload_lds16(gp, As + (wv * 4 + k * 16) * 128);
  }
#else
  for (int i = t; i < 2048; i += 256) {
    int r = i >> 4, cc = i & 15;
    float4 v = *(const float4*)(A + (size_t)(row0 + r) * 128 + cc * 8);
    *(float4*)(As + r * 128 + ((cc ^ (r & 15)) << 3)) = v;
  }
#endif
  for (int ct = 0; ct < ntiles; ++ct) {
    const int col0 = (blockIdx.y * ntiles + ct) * 64;
#if HAVE_GLL
#pragma unroll
    for (int k = 0; k < 4; ++k) {
      int c = wv * 4 + k * 16 + rsub;
      const f16* gp = WT + (size_t)(col0 + c) * ldw + ((c8 ^ (c & 15)) << 3);
      gload_lds16(gp, Bs + (wv * 4 + k * 16) * 128);
    }
#else
    for (int i = t; i < 1024; i += 256) {
      int c = i >> 4, cc = i & 15;
      float4 v = *(const float4*)(WT + (size_t)(col0 + c) * ldw + cc * 8);
      *(float4*)(Bs + c * 128 + ((cc ^ (c & 15)) << 3)) = v;
    }
#endif
    __syncthreads();
    f32x4 acc[2][4];
#pragma unroll
    for (int m = 0; m < 2; ++m)
#pragma unroll
      for (int n = 0; n < 4; ++n) acc[m][n] = (f32x4){0.f, 0.f, 0.f, 0.f};
#pragma unroll
    for (int ks = 0; ks < 4; ++ks) {
      const int co = (((ks * 4 + l4) ^ l15) << 3);
      f16x8 a0 = *(const f16x8*)(As + (wv * 32 +      l15) * 128 + co);
      f16x8 a1 = *(const f16x8*)(As + (wv * 32 + 16 + l15) * 128 + co);
      f16x8 b0 = *(const f16x8*)(Bs + (     l15) * 128 + co);
      f16x8 b1 = *(const f16x8*)(Bs + (16 + l15) * 128 + co);
      f16x8 b2 = *(const f16x8*)(Bs + (32 + l15) * 128 + co);
      f16x8 b3 = *(const f16x8*)(Bs + (48 + l15) * 128 + co);
      acc[0][0] = __builtin_amdgcn_mfma_f32_16x16x32_f16(a0, b0, acc[0][0], 0, 0, 0);
      acc[0][1] = __builtin_amdgcn_mfma_f32_16x16x32_f16(a0, b1, acc[0][1], 0, 0, 0);
      acc[0][2] = __builtin_amdgcn_mfma_f32_16x16x32_f16(a0, b2, acc[0][2], 0, 0, 0);
      acc[0][3] = __builtin_amdgcn_mfma_f32_16x16x32_f16(a0, b3, acc[0][3], 0, 0, 0);
      acc[1][0] = __builtin_amdgcn_mfma_f32_16x16x32_f16(a1, b0, acc[1][0], 0, 0, 0);
      acc[1][1] = __builtin_amdgcn_mfma_f32_16x16x32_f16(a1, b1, acc[1][1], 0, 0, 0);
      acc[1][2] = __builtin_amdgcn_mfma_f32_16x16x32_f16(a1, b2, acc[1][2], 0, 0, 0);
      acc[1][3] = __builtin_amdgcn_mfma_f32_16x16x32_f16(a1, b3, acc[1][3], 0, 0, 0);
    }
    __syncthreads();
#pragma unroll
    for (int m = 0; m < 2; ++m) {
#pragma unroll
      for (int j = 0; j < 4; ++j) {
        int r = row0 + wv * 32 + m * 16 + l4 * 4 + j;
#pragma unroll
        for (int n = 0; n < 4; ++n) {
          int cc = col0 + n * 16 + l15;
          f16 v = (f16)acc[m][n][j];
          if (mode == 0) {
            Os[(size_t)r * 384 + cc] = v;
          } else if (r < 280) {
            int c;
            if (r < 128)      c = hh * 128 + r;
            else if (r < 256) c = 384 + hh * 128 + (r - 128);
            else              c = 768 + hh * 24 + (r - 256);
            Os[(size_t)c * 128 + cc] = v;
          }
        }
      }
    }
  }
}

// ========== hgemm2: 128-row tile, general-K, dual A, GLL staging, fused relu+resid ==========
// ctrOut != null: append mini-GEMM  ctrOut[r][c] = h3tile[r]@ctrW[k<128] + h[r]@ctrW[k>=128] + ctrB
__global__ __launch_bounds__(256) void hgemm2_kernel(
    const f16* __restrict__ A, int lda,
    const f16* __restrict__ A2, int lda2, int a2k,
    const f16* __restrict__ WT, int K,
    const float* __restrict__ bias,
    f16* __restrict__ outb, int ldb,
    const f16* __restrict__ fresid, int ldr,
    int dorelu, int M,
    const f16* __restrict__ ctrW, const float* __restrict__ ctrB,
    float* __restrict__ ctrOut)
{
  __shared__ f16 As[128 * 128];
  __shared__ f16 Bs[128 * 128];
  const int t = threadIdx.x;
  const int wv = t >> 6, lane = t & 63;
  const int l15 = lane & 15, l4 = lane >> 4;
  const int c8 = lane & 15, rsub = lane >> 4;
  const int row0 = blockIdx.x * 128;
  const int col0 = blockIdx.y * 128;

  f32x4 acc[2][8];
#pragma unroll
  for (int m = 0; m < 2; ++m)
#pragma unroll
    for (int n = 0; n < 8; ++n) acc[m][n] = (f32x4){0.f, 0.f, 0.f, 0.f};

  for (int kc = 0; kc < K; kc += 128) {
    const f16* Ap; int koff, ldA;
    if (kc >= a2k) { Ap = A2; koff = kc - a2k; ldA = lda2; }
    else           { Ap = A;  koff = kc;       ldA = lda;  }
#if HAVE_GLL
#pragma unroll
    for (int k = 0; k < 8; ++k) {
      int r = wv * 4 + k * 16 + rsub;
      int rc = row0 + r; if (rc >= M) rc = M - 1;
      const f16* gp = Ap + (size_t)rc * ldA + koff + ((c8 ^ (r & 15)) << 3);
      gload_lds16(gp, As + (wv * 4 + k * 16) * 128);
    }
#pragma unroll
    for (int k = 0; k < 8; ++k) {
      int c = wv * 4 + k * 16 + rsub;
      const f16* gp = WT + (size_t)(col0 + c) * K + kc + ((c8 ^ (c & 15)) << 3);
      gload_lds16(gp, Bs + (wv * 4 + k * 16) * 128);
    }
#else
    for (int i = t; i < 2048; i += 256) {
      int r = i >> 4, cc = i & 15;
      int gr = row0 + r; if (gr >= M) gr = M - 1;
      float4 v = *(const float4*)(Ap + (size_t)gr * ldA + koff + cc * 8);
      *(float4*)(As + r * 128 + ((cc ^ (r & 15)) << 3)) = v;
    }
    for (int i = t; i < 2048; i += 256) {
      int c = i >> 4, cc = i & 15;
      float4 v = *(const float4*)(WT + (size_t)(col0 + c) * K + kc + cc * 8);
      *(float4*)(Bs + c * 128 + ((cc ^ (c & 15)) << 3)) = v;
    }
#endif
    __syncthreads();
#pragma unroll
    for (int ks = 0; ks < 4; ++ks) {
      const int co = (((ks * 4 + l4) ^ l15) << 3);
      f16x8 a0 = *(const f16x8*)(As + (wv * 32 +      l15) * 128 + co);
      f16x8 a1 = *(const f16x8*)(As + (wv * 32 + 16 + l15) * 128 + co);
#pragma unroll
      for (int n = 0; n < 8; ++n) {
        f16x8 b = *(const f16x8*)(Bs + (n * 16 + l15) * 128 + co);
        acc[0][n] = __builtin_amdgcn_mfma_f32_16x16x32_f16(a0, b, acc[0][n], 0, 0, 0);
        acc[1][n] = __builtin_amdgcn_mfma_f32_16x16x32_f16(a1, b, acc[1][n], 0, 0, 0);
      }
    }
    __syncthreads();
  }

  float bv8[8];
#pragma unroll
  for (int n = 0; n < 8; ++n) bv8[n] = bias ? bias[col0 + n * 16 + l15] : 0.f;
#pragma unroll
  for (int m = 0; m < 2; ++m) {
#pragma unroll
    for (int j = 0; j < 4; ++j) {
      int rl = wv * 32 + m * 16 + l4 * 4 + j;
      int r = row0 + rl;
#pragma unroll
      for (int n = 0; n < 8; ++n) {
        int c = col0 + n * 16 + l15;
        float val = acc[m][n][j] + bv8[n];
        if (fresid) val += (float)fresid[(size_t)r * ldr + c];
        if (dorelu) val = fmaxf(val, 0.f);
        f16 hv = (f16)val;
        if (r < M) outb[(size_t)r * ldb + c] = hv;
        if (ctrOut)   // stash h3 tile into As (swizzled [row][k])
          As[rl * 128 + (((c >> 3) ^ (rl & 15)) << 3) + (c & 7)] = hv;
      }
    }
  }

  if (ctrOut) {
    // Bs <- ctrW k<128 half (h3 part)
    for (int i = t; i < 2048; i += 256) {
      int c = i >> 4, k8 = i & 15;
      float4 v = *(const float4*)(ctrW + (size_t)c * 256 + k8 * 8);
      *(float4*)(Bs + c * 128 + ((k8 ^ (c & 15)) << 3)) = v;
    }
    __syncthreads();
    f32x4 acc2[2][8];
#pragma unroll
    for (int m = 0; m < 2; ++m)
#pragma unroll
      for (int n = 0; n < 8; ++n) acc2[m][n] = (f32x4){0.f, 0.f, 0.f, 0.f};
#pragma unroll
    for (int ks = 0; ks < 4; ++ks) {
      const int co = (((ks * 4 + l4) ^ l15) << 3);
      f16x8 a0 = *(const f16x8*)(As + (wv * 32 +      l15) * 128 + co);
      f16x8 a1 = *(const f16x8*)(As + (wv * 32 + 16 + l15) * 128 + co);
#pragma unroll
      for (int n = 0; n < 8; ++n) {
        f16x8 b = *(const f16x8*)(Bs + (n * 16 + l15) * 128 + co);
        acc2[0][n] = __builtin_amdgcn_mfma_f32_16x16x32_f16(a0, b, acc2[0][n], 0, 0, 0);
        acc2[1][n] = __builtin_amdgcn_mfma_f32_16x16x32_f16(a1, b, acc2[1][n], 0, 0, 0);
      }
    }
    __syncthreads();
    // As <- h tile (xh h-half via A2), Bs <- ctrW k>=128 half
    for (int i = t; i < 2048; i += 256) {
      int r = i >> 4, k8 = i & 15;
      int gr = row0 + r; if (gr >= M) gr = M - 1;
      float4 v = *(const float4*)(A2 + (size_t)gr * lda2 + 128 + k8 * 8);
      *(float4*)(As + r * 128 + ((k8 ^ (r & 15)) << 3)) = v;
    }
    for (int i = t; i < 2048; i += 256) {
      int c = i >> 4, k8 = i & 15;
      float4 v = *(const float4*)(ctrW + (size_t)c * 256 + 128 + k8 * 8);
      *(float4*)(Bs + c * 128 + ((k8 ^ (c & 15)) << 3)) = v;
    }
    __syncthreads();
#pragma unroll
    for (int ks = 0; ks < 4; ++ks) {
      const int co = (((ks * 4 + l4) ^ l15) << 3);
      f16x8 a0 = *(const f16x8*)(As + (wv * 32 +      l15) * 128 + co);
      f16x8 a1 = *(const f16x8*)(As + (wv * 32 + 16 + l15) * 128 + co);
#pragma unroll
      for (int n = 0; n < 8; ++n) {
        f16x8 b = *(const f16x8*)(Bs + (n * 16 + l15) * 128 + co);
        acc2[0][n] = __builtin_amdgcn_mfma_f32_16x16x32_f16(a0, b, acc2[0][n], 0, 0, 0);
        acc2[1][n] = __builtin_amdgcn_mfma_f32_16x16x32_f16(a1, b, acc2[1][n], 0, 0, 0);
      }
    }
#pragma unroll
    for (int m = 0; m < 2; ++m) {
#pragma unroll
      for (int j = 0; j < 4; ++j) {
        int r = row0 + wv * 32 + m * 16 + l4 * 4 + j;
        if (r >= M) continue;
#pragma unroll
        for (int n = 0; n < 8; ++n) {
          int c = n * 16 + l15;
          ctrOut[(size_t)r * 128 + c] = acc2[m][n][j] + ctrB[c];
        }
      }
    }
  }
}

// ================= CSR build =================
__global__ void zero_int_kernel(int* __restrict__ p, int n) {
  int i = blockIdx.x * 256 + threadIdx.x;
  if (i < n) p[i] = 0;
}
__global__ void hist_kernel(const int* __restrict__ dst, int* __restrict__ deg) {
  int e = blockIdx.x * 256 + threadIdx.x;
  if (e < NE) atomicAdd(&deg[dst[e]], 1);
}
__global__ void scanA_kernel(const int* __restrict__ deg, int* __restrict__ rowstart,
                             int* __restrict__ part) {
  __shared__ int sd[256];
  int b = blockIdx.x, t = threadIdx.x, i = b * 256 + t;
  sd[t] = (i < NN) ? deg[i] : 0;
  __syncthreads();
  for (int o = 1; o < 256; o <<= 1) {
    int v = (t >= o) ? sd[t - o] : 0;
    __syncthreads();
    sd[t] += v;
    __syncthreads();
  }
  if (i < NN) rowstart[i + 1] = sd[t];
  if (t == 255) part[b] = sd[255];
}
__global__ void scanB_kernel(int* __restrict__ part, int nb) {
  __shared__ int sd[256];
  int t = threadIdx.x;
  sd[t] = (t < nb) ? part[t] : 0;
  __syncthreads();
  for (int o = 1; o < 256; o <<= 1) {
    int v = (t >= o) ? sd[t - o] : 0;
    __syncthreads();
    sd[t] += v;
    __syncthreads();
  }
  if (t < nb) part[t] = sd[t];
}
__global__ void scanC_kernel(const int* __restrict__ deg, int* __restrict__ rowstart,
                             const int* __restrict__ part, int* __restrict__ cursor) {
  int b = blockIdx.x, t = threadIdx.x, i = b * 256 + t;
  if (i >= NN) return;
  int off = b ? part[b - 1] : 0;
  int fin = rowstart[i + 1] + off;
  rowstart[i + 1] = fin;
  cursor[i] = fin - deg[i];
  if (i == 0) rowstart[0] = 0;
}
__global__ void scatter_kernel(const int* __restrict__ dst, const int* __restrict__ src,
                               const float* __restrict__ dirw, const float* __restrict__ geo,
                               int* __restrict__ cursor,
                               int* __restrict__ srcp, f16* __restrict__ dirpb,
                               f16* __restrict__ geop) {
  int e = blockIdx.x * 256 + threadIdx.x;
  if (e < NE) {
    int pos = atomicAdd(&cursor[dst[e]], 1);
    srcp[pos] = src[e];
    float dv = dirw[e];
    dirpb[pos] = (f16)dv;
    f16* gp = geop + (size_t)pos * 24;
#pragma unroll
    for (int j = 0; j < 20; ++j) gp[j] = (f16)geo[(size_t)e * 20 + j];
    gp[20] = (f16)dv;
    gp[21] = (f16)0.f; gp[22] = (f16)0.f; gp[23] = (f16)0.f;
  }
}

// ========== prep inputs: Vf16 (gathered Wee rows + bee), WeT16, Wq16, Wk16 ==========
__global__ void convert_kernel(const float* __restrict__ Wee, const float* __restrict__ bee,
                               const float* __restrict__ WeAll, const float* __restrict__ Wq,
                               const float* __restrict__ Wk,
                               f16* __restrict__ Vf, f16* __restrict__ WeT,
                               f16* __restrict__ Wq16, f16* __restrict__ Wk16)
{
  int idx = blockIdx.x * 256 + threadIdx.x;
  if (idx < 49152) {                       // Vf [384 rows][128]
    int r = idx >> 7, j = idx & 127;
    float v = 0.f;
    if (r < 128)       v = Wee[(size_t)(128 + r) * 128 + j];   // U rows (h[src]*dir block)
    else if (r < 256)  v = Wee[(size_t)(r - 128) * 128 + j];   // T rows (h[dst] block)
    else if (r < 276)  v = Wee[(size_t)(257 + (r - 256)) * 128 + j];  // geo rows
    else if (r == 276) v = Wee[(size_t)256 * 128 + j];         // dir row (t=20)
    else if (r == 277) v = bee[j];
    Vf[idx] = (f16)v;
  } else if (idx < 196608) {               // WeT16[i][c(384)][j(128)] = We[i][j][c]
    int rr = idx - 49152; int i = rr / 49152; int r2 = rr % 49152;
    int cc = r2 >> 7, j = r2 & 127;
    WeT[rr] = (f16)WeAll[((size_t)i * 128 + j) * 384 + cc];
  } else if (idx < 344064) {               // Wq16 straight convert
    int rr = idx - 196608;
    Wq16[rr] = (f16)Wq[rr];
  } else if (idx < 491520) {               // Wk16 straight convert
    int rr = idx - 344064;
    Wk16[rr] = (f16)Wk[rr];
  }
}

// ========== postS: Arows + W2bigT + biasAB (all depend only on Sall/Wk16/raw weights) ==========
__global__ void postS_kernel(const f16* __restrict__ Wk16, const f16* __restrict__ Sall,
                             const float* __restrict__ beAll, const float* __restrict__ Wv,
                             const float* __restrict__ bv, const float* __restrict__ Ws,
                             const float* __restrict__ Wres, const float* __restrict__ bq,
                             f16* __restrict__ Arows, f16* __restrict__ W2bigT,
                             float* __restrict__ biasAB)
{
  int idx = blockIdx.x * 256 + threadIdx.x;
  if (idx < 442368) {                      // Arows[z=(i,h)][384 rows][128]
    int z = idx / 49152; int rr = idx % 49152; int r = rr >> 7; int k2 = rr & 127;
    int i = z / 3, h = z % 3;
    f16 v = (f16)0.f;
    if (r < 128)       v = Wk16[(size_t)i * 49152 + (size_t)r * 384 + h * 128 + k2];
    else if (r < 256)  v = Sall[(size_t)i * 147456 + (size_t)(r - 128) * 384 + h * 128 + k2];
    else if (r < 277)  v = Sall[(size_t)i * 147456 + (size_t)r * 384 + h * 128 + k2];
    Arows[idx] = v;
  } else if (idx < 884736) {               // W2bigT[3l][128c][1152k]
    int r0 = idx - 442368;
    int i = r0 / 147456; int r = r0 % 147456; int c = r / 1152; int k = r % 1152;
    const f16* S = Sall + (size_t)i * 147456;
    float v = 0.f;
    if (k < 384) {
      int h = k >> 7, tt = k & 127;
      v = (float)S[(size_t)tt * 384 + h * 128 + c];
    } else if (k < 768) {
      int h = (k - 384) >> 7, u = (k - 384) & 127;
      v = Wv[((size_t)i * 128 + u) * 384 + h * 128 + c];
    } else if (k < 840) {
      int h = (k - 768) / 24, tt = (k - 768) % 24;
      if (tt < 21)       v = (float)S[(size_t)(256 + tt) * 384 + h * 128 + c];
      else if (tt == 21) v = (float)S[(size_t)277 * 384 + h * 128 + c]
                           + beAll[i * 384 + h * 128 + c] + bv[i * 384 + h * 128 + c];
    } else if (k < 896) {
      v = 0.f;
    } else if (k < 1024) {
      int tt = k - 896;
      v = ((float)S[(size_t)(128 + tt) * 384 + c]
         + (float)S[(size_t)(128 + tt) * 384 + 128 + c]
         + (float)S[(size_t)(128 + tt) * 384 + 256 + c]) * (1.0f / 3.0f);
    } else {
      v = Ws[((size_t)i * 128 + (k - 1024)) * 128 + c];
      if (i == 0) v += Wres[(k - 1024) * 128 + c];
    }
    W2bigT[(size_t)i * 147456 + c * 1152 + k] = (f16)v;
  } else if (idx < 887424) {               // biasAB[3][896]
    int r = idx - 884736; int i = r / 896; int c = r % 896;
    float acc = 0.f;
    int h = 0, ro = -1;
    if (c < 384)      { h = c >> 7;         ro = c & 127; }
    else if (c < 768) { h = (c - 384) >> 7; ro = 128 + ((c - 384) & 127); }
    else if (c < 840) { h = (c - 768) / 24; ro = 256 + ((c - 768) % 24); }
    if (ro >= 0) {
      const f16* ar = Arows + ((size_t)(i * 3 + h)) * 49152 + (size_t)ro * 128;
      const float* bqh = bq + i * 384 + h * 128;
      for (int k2 = 0; k2 < 128; ++k2) acc += (float)ar[k2] * bqh[k2];
    }
    biasAB[r] = acc;
  }
}

// ========== misc: hconv (h->xh both halves) + WctrT2 + bias0 ==========
__global__ void misc_kernel(const float* __restrict__ src, f16* __restrict__ xh,
                            const float* __restrict__ Wctr, const float* __restrict__ bs,
                            const float* __restrict__ bres,
                            f16* __restrict__ WctrT2, float* __restrict__ bias0)
{
  int idx = blockIdx.x * 256 + threadIdx.x;
  if (idx < NN * 32) {
    float4 a = ((const float4*)src)[idx];
    f16x4 o;
    o[0] = (f16)a.x; o[1] = (f16)a.y; o[2] = (f16)a.z; o[3] = (f16)a.w;
    int r = idx >> 5, c4 = idx & 31;
    *(f16x4*)(xh + (size_t)r * 256 + c4 * 4) = o;
    *(f16x4*)(xh + (size_t)r * 256 + 128 + c4 * 4) = o;
  } else if (idx < NN * 32 + 32768) {
    int r = idx - NN * 32;
    int c = r >> 8, k = r & 255;
    float v = (k < 128) ? Wctr[(size_t)(128 + k) * 128 + c]
                        : Wctr[(size_t)(k - 128) * 128 + c];
    WctrT2[r] = (f16)v;
  } else if (idx < NN * 32 + 32896) {
    int c = idx - NN * 32 - 32768;
    bias0[c] = bs[c] + bres[c];
  }
}

// ========== attention (proven): 16 lanes/node, 2-edge unroll, xh-interleaved gather ==========
__global__ __launch_bounds__(256) void attn_kernel(
    const f16* __restrict__ xh,     // [N][256] = [x | h]
    f16* __restrict__ nbuf,
    const int* __restrict__ rowstart,
    const int* __restrict__ srcp,
    const f16* __restrict__ dirpb,
    const f16* __restrict__ geop)
{
  const int sl = threadIdx.x & 15;
  const int n = blockIdx.x * 16 + (threadIdx.x >> 4);
  const float rsC = 0.088388347648318447f;  // 1/sqrt(128)
  f16* row = nbuf + (size_t)n * 1024;

  f16x8 qk[3], g2[3];
#pragma unroll
  for (int h = 0; h < 3; ++h) {
    qk[h] = *(const f16x8*)(row + h * 128 + sl * 8);
    g2[h] = *(const f16x8*)(row + 384 + h * 128 + sl * 8);
  }
  float g34a[3], g34c[3];
#pragma unroll
  for (int h = 0; h < 3; ++h) {
    g34a[h] = (float)row[768 + h * 24 + sl];
    g34c[h] = (sl < 8) ? (float)row[768 + h * 24 + 16 + sl] : 0.f;
  }
  float den[3] = {0.f, 0.f, 0.f};
  float F2[3][8], Fv[3][8];
#pragma unroll
  for (int h = 0; h < 3; ++h)
#pragma unroll
    for (int j = 0; j < 8; ++j) { F2[h][j] = 0.f; Fv[h][j] = 0.f; }
  float f34a[3] = {0.f, 0.f, 0.f}, f34c[3] = {0.f, 0.f, 0.f};

  const int beg = rowstart[n], end = rowstart[n + 1];
  int ii = beg;
  for (; ii + 1 < end; ii += 2) {
    const int s0 = srcp[ii], s1 = srcp[ii + 1];
    const float d0 = (float)dirpb[ii], d1 = (float)dirpb[ii + 1];
    const f16* p0 = xh + (size_t)s0 * 256 + sl * 8;
    const f16* p1 = xh + (size_t)s1 * 256 + sl * 8;
    f16x8 xv0 = *(const f16x8*)p0;
    f16x8 hv0 = *(const f16x8*)(p0 + 128);
    f16x8 xv1 = *(const f16x8*)p1;
    f16x8 hv1 = *(const f16x8*)(p1 + 128);
    const float gea0 = (float)geop[(size_t)ii * 24 + sl];
    const float geb0 = (sl < 8) ? (float)geop[(size_t)ii * 24 + 16 + sl] : 0.f;
    const float gea1 = (float)geop[(size_t)(ii + 1) * 24 + sl];
    const float geb1 = (sl < 8) ? (float)geop[(size_t)(ii + 1) * 24 + 16 + sl] : 0.f;

    float pa[6];
#pragma unroll
    for (int h = 0; h < 3; ++h) {
      pa[h]     = dot8(qk[h], xv0, 0.f) + d0 * dot8(g2[h], hv0, 0.f)
                + gea0 * g34a[h] + geb0 * g34c[h];
      pa[3 + h] = dot8(qk[h], xv1, 0.f) + d1 * dot8(g2[h], hv1, 0.f)
                + gea1 * g34a[h] + geb1 * g34c[h];
    }
#pragma unroll
    for (int off = 1; off < 16; off <<= 1) {
#pragma unroll
      for (int q = 0; q < 6; ++q) pa[q] += __shfl_xor(pa[q], off);
    }
    float w0[3], w1[3];
#pragma unroll
    for (int h = 0; h < 3; ++h) {
      w0[h] = __expf(pa[h] * rsC);
      w1[h] = __expf(pa[3 + h] * rsC);
      den[h] += w0[h] + w1[h];
    }
#pragma unroll
    for (int h = 0; h < 3; ++h) {
      const float wd0 = w0[h] * d0, wd1 = w1[h] * d1;
#pragma unroll
      for (int j = 0; j < 8; ++j) {
        F2[h][j] = fmaf(wd0, (float)hv0[j], fmaf(wd1, (float)hv1[j], F2[h][j]));
        Fv[h][j] = fmaf(w0[h], (float)xv0[j], fmaf(w1[h], (float)xv1[j], Fv[h][j]));
      }
      f34a[h] = fmaf(w0[h], gea0, fmaf(w1[h], gea1, f34a[h]));
      f34c[h] = fmaf(w0[h], geb0, fmaf(w1[h], geb1, f34c[h]));
    }
  }
  if (ii < end) {
    const int s0 = srcp[ii];
    const float d0 = (float)dirpb[ii];
    const f16* p0 = xh + (size_t)s0 * 256 + sl * 8;
    f16x8 xv0 = *(const f16x8*)p0;
    f16x8 hv0 = *(const f16x8*)(p0 + 128);
    const float gea0 = (float)geop[(size_t)ii * 24 + sl];
    const float geb0 = (sl < 8) ? (float)geop[(size_t)ii * 24 + 16 + sl] : 0.f;
    float pa[3];
#pragma unroll
    for (int h = 0; h < 3; ++h)
      pa[h] = dot8(qk[h], xv0, 0.f) + d0 * dot8(g2[h], hv0, 0.f)
            + gea0 * g34a[h] + geb0 * g34c[h];
#pragma unroll
    for (int off = 1; off < 16; off <<= 1) {
#pragma unroll
      for (int q = 0; q < 3; ++q) pa[q] += __shfl_xor(pa[q], off);
    }
#pragma unroll
    for (int h = 0; h < 3; ++h) {
      const float w = __expf(pa[h] * rsC);
      den[h] += w;
      const float wd = w * d0;
#pragma unroll
      for (int j = 0; j < 8; ++j) {
        F2[h][j] = fmaf(wd, (float)hv0[j], F2[h][j]);
        Fv[h][j] = fmaf(w, (float)xv0[j], Fv[h][j]);
      }
      f34a[h] = fmaf(w, gea0, f34a[h]);
      f34c[h] = fmaf(w, geb0, f34c[h]);
    }
  }

  float sc[3], swh[3];
#pragma unroll
  for (int h = 0; h < 3; ++h) {
    sc[h] = (1.f / 3.f) / (den[h] + 1e-16f);
    swh[h] = den[h] * sc[h];
  }
#pragma unroll
  for (int h = 0; h < 3; ++h) {
    f16x8 o1, o2;
#pragma unroll
    for (int j = 0; j < 8; ++j) {
      o1[j] = (f16)(F2[h][j] * sc[h]);
      o2[j] = (f16)(Fv[h][j] * sc[h]);
    }
    *(f16x8*)(row + h * 128 + sl * 8) = o1;
    *(f16x8*)(row + 384 + h * 128 + sl * 8) = o2;
  }
#pragma unroll
  for (int h = 0; h < 3; ++h) {
    row[768 + h * 24 + sl] = (f16)(f34a[h] * sc[h]);
    if (sl < 8) {
      float fcv = (sl == 5) ? swh[h] : f34c[h] * sc[h];
      row[768 + h * 24 + 16 + sl] = (f16)fcv;
    }
  }
  // masked h -> cols 896..1023 (feeds Wsum0 block of the output GEMM)
  f16x8 ho = *(const f16x8*)(xh + (size_t)n * 256 + 128 + sl * 8);
  if (beg >= end) {
#pragma unroll
    for (int j = 0; j < 8; ++j) ho[j] = (f16)0.f;
  }
  *(f16x8*)(row + 896 + sl * 8) = ho;
}

// ================= launch =================
extern "C" void kernel_launch(void* const* d_in, const int* in_sizes, int n_in,
                              void* d_out, int out_size, void* d_ws, size_t ws_size,
                              hipStream_t stream)
{
  (void)in_sizes; (void)n_in; (void)out_size; (void)ws_size;
  const float* h    = (const float*)d_in[0];
  const float* geo  = (const float*)d_in[1];
  const float* dirw = (const float*)d_in[2];
  const int*   src  = (const int*)d_in[3];
  const int*   dst  = (const int*)d_in[4];
  const float* Wee  = (const float*)d_in[5];
  const float* bee  = (const float*)d_in[6];
  const float* Wres = (const float*)d_in[7];
  const float* bres = (const float*)d_in[8];
  const float* Wq   = (const float*)d_in[9];
  const float* bq   = (const float*)d_in[10];
  const float* Wk   = (const float*)d_in[11];
  const float* bk   = (const float*)d_in[12];  (void)bk;   // cancels in softmax
  const float* Wv   = (const float*)d_in[13];
  const float* bv   = (const float*)d_in[14];
  const float* We   = (const float*)d_in[15];
  const float* be   = (const float*)d_in[16];
  const float* Ws   = (const float*)d_in[17];
  const float* bs   = (const float*)d_in[18];
  const float* Wctr = (const float*)d_in[19];
  const float* bctr = (const float*)d_in[20];

  char* base = (char*)d_ws;
  size_t off = 0;
  auto take = [&](size_t bytes) -> char* {
    char* p = base + off;
    off += bytes;
    off = (off + 255) & ~(size_t)255;
    return p;
  };
  f16* nbuf     = (f16*)take((size_t)NN * 1024 * 2);
  f16* xh       = (f16*)take((size_t)NN * 256 * 2);
  f16* Vf16     = (f16*)take(49152 * 2);
  f16* WeT16    = (f16*)take((size_t)3 * 49152 * 2);
  f16* Wq16     = (f16*)take((size_t)3 * 49152 * 2);
  f16* Wk16     = (f16*)take((size_t)3 * 49152 * 2);
  f16* Sall     = (f16*)take((size_t)3 * 147456 * 2);
  f16* Arows    = (f16*)take((size_t)9 * 49152 * 2);
  f16* WABT     = (f16*)take((size_t)3 * 114688 * 2);
  float* biasAB = (float*)take((size_t)3 * 896 * 4);
  f16* W2bigT   = (f16*)take((size_t)3 * 147456 * 2);
  f16* WctrT2   = (f16*)take(32768 * 2);
  float* bias0  = (float*)take(128 * 4);
  f16* dirpb    = (f16*)take((size_t)NE * 2);
  f16* geop     = (f16*)take((size_t)NE * 24 * 2);
  int* deg      = (int*)take((size_t)NN * 4);
  int* rowstart = (int*)take((size_t)(NN + 1) * 4);
  int* cursor   = (int*)take((size_t)NN * 4);
  int* srcp     = (int*)take((size_t)NE * 4);
  int* part     = (int*)take(256 * 4);

  // CSR by dst
  zero_int_kernel<<<(NN + 255) / 256, 256, 0, stream>>>(deg, NN);
  hist_kernel<<<(NE + 255) / 256, 256, 0, stream>>>(dst, deg);
  scanA_kernel<<<196, 256, 0, stream>>>(deg, rowstart, part);
  scanB_kernel<<<1, 256, 0, stream>>>(part, 196);
  scanC_kernel<<<196, 256, 0, stream>>>(deg, rowstart, part, cursor);
  scatter_kernel<<<(NE + 255) / 256, 256, 0, stream>>>(dst, src, dirw, geo, cursor,
                                                       srcp, dirpb, geop);
  misc_kernel<<<(NN * 32 + 32896 + 255) / 256, 256, 0, stream>>>(h, xh, Wctr, bs, bres,
                                                                 WctrT2, bias0);
  // ---- weight prep via MFMA GEMMs ----
  convert_kernel<<<(491520 + 255) / 256, 256, 0, stream>>>(Wee, bee, We, Wq, Wk,
                                                           Vf16, WeT16, Wq16, Wk16);
  pgemm_kernel<<<dim3(3, 2, 3), 256, 0, stream>>>(Vf16, WeT16, Sall, 0);      // S = V@We
  postS_kernel<<<(887424 + 255) / 256, 256, 0, stream>>>(Wk16, Sall, be, Wv, bv, Ws,
                                                         Wres, bq, Arows, W2bigT, biasAB);
  pgemm_kernel<<<dim3(3, 2, 9), 256, 0, stream>>>(Arows, Wq16, WABT, 1);      // WABT

  for (int i = 0; i < 3; ++i) {
    // fat: x @ [qk|g2|g34|0] -> nbuf cols 0..895
    hgemm_k128_kernel<<<dim3(391, 2), 256, 0, stream>>>(xh, 256, WABT + (size_t)i * 114688,
        biasAB + (size_t)i * 896, nbuf, 1024, NN, 7);
    // attention: rewrites nbuf cols 0..839, writes masked-h to 896..1023
    attn_kernel<<<3125, 256, 0, stream>>>(xh, nbuf, rowstart, srcp, dirpb, geop);
    // out: x_new = relu([F2|Fv|fg|0|mask*h| x(A2)] @ W2big + bias (+x resid for i>0)) -> xh x-half
    // layer 2 additionally fuses the final ctr GEMM: d_out = [h3|h] @ WctrT2 + bctr
    const float* obias = (i == 0) ? bias0 : (bs + i * 128);
    const f16* resid = (i == 0) ? nullptr : xh;   // layer0 residual folded into W2bigT/bias0
    const f16* ctrW = (i == 2) ? WctrT2 : nullptr;
    const float* ctrB = (i == 2) ? bctr : nullptr;
    float* ctrOut = (i == 2) ? (float*)d_out : nullptr;
    hgemm2_kernel<<<dim3(391, 1), 256, 0, stream>>>(nbuf, 1024, xh, 256, 1024,
        W2bigT + (size_t)i * 147456, 1152, obias, xh, 256,
        resid, 256, 1, NN, ctrW, ctrB, ctrOut);
  }
}